// Round 5
// baseline (259.987 us; speedup 1.0000x reference)
//
#include <hip/hip_runtime.h>
#include <math.h>

#define B 8
#define C 256
#define L 2046
#define LP 2048
#define IC 64
#define OC 128
#define BN_EPS 1e-5f
#define INVN (1.f / 16384.f)   // 1/(B*LP)

// ws offsets (float units)
#define OFF_Y1T    0u          // conv1 out (pre-BN) bf16 [b][l][64]
#define OFF_Y2C    524288u     // conv1 out (pre-BN) bf16 [b][64][l]
#define OFF_SAFT   1048576u    // sa_feat bf16 [b][l][64]
#define OFF_SCFT   1572864u    // sc_feat bf16 [b][l][64]
#define OFF_Y51T   2097152u    // conv3 out (pre-BN) bf16 [b][l][64]
#define OFF_Y52T   2621440u
#define OFF_VB     3145728u    // v bf16 [b][64][l]
#define OFF_QT     3670016u    // q bf16 [b][l][8]
#define OFF_KT     3735552u
#define OFF_LPART  3801088u    // pam denominators [b][32][4][64]
#define OFF_EPART  3866624u    // CAM gram partials [b][64][64][64]
#define OFF_ATTN   5963776u
#define OFF_PART1  5996544u    // stats partials [256 slots][256 blk]
#define OFF_PART2  6062080u
#define OFF_COEF1  6127616u    // (A,B) per channel [128][2]
#define OFF_COEF2  6127872u
#define OFF_FSUM   6128128u    // [b][64] atomic
#define OFF_W5BF   6128640u    // bf16 [128][256]
#define OFF_W67    6145024u    // bf16 [2][128][64]
#define OFF_WT     6153216u    // bf16 [2][3][64][64]
#define OFF_WQKV   6165504u    // bf16 [80][64]
#define OFF_BQKV   6168064u    // fp32 [80]

typedef __attribute__((ext_vector_type(8))) short bshort8;
typedef __attribute__((ext_vector_type(4))) float f32x4;

__device__ __forceinline__ unsigned short f2bf(float f) {
    union { float f; unsigned int u; } v; v.f = f;
    unsigned int r = v.u + 0x7fffu + ((v.u >> 16) & 1u);
    return (unsigned short)(r >> 16);
}
__device__ __forceinline__ float bf2f(unsigned short u) {
    union { unsigned int i; float f; } v; v.i = ((unsigned int)u) << 16;
    return v.f;
}
__device__ __forceinline__ unsigned int pk2(float a, float b) {
    return (unsigned int)f2bf(a) | ((unsigned int)f2bf(b) << 16);
}

// ---- weight prep + FSUM zero ----
__global__ __launch_bounds__(256) void k_wprep(
        const float* __restrict__ W5a, const float* __restrict__ W5c,
        const float* __restrict__ W6, const float* __restrict__ W7,
        const float* __restrict__ W51, const float* __restrict__ W52,
        const float* __restrict__ Wq, const float* __restrict__ Wk,
        const float* __restrict__ Wv, const float* __restrict__ bq,
        const float* __restrict__ bk, const float* __restrict__ bv,
        unsigned short* __restrict__ W5BF, unsigned short* __restrict__ W67,
        unsigned short* __restrict__ WT, unsigned short* __restrict__ WQKV,
        float* __restrict__ BQKV, float* __restrict__ FSUM) {
    int i = blockIdx.x * 256 + threadIdx.x;
    if (i < 32768) {
        int o = i >> 8, c = i & 255;
        W5BF[i] = f2bf(o < 64 ? W5a[o * 256 + c] : W5c[(o - 64) * 256 + c]);
    } else if (i < 49152) {
        int j = i - 32768; int g = j >> 13; int r = j & 8191;
        W67[j] = f2bf(g ? W7[r] : W6[r]);
    } else if (i < 73728) {
        int j = i - 49152;
        int c = j & 63, o = (j >> 6) & 63, wt = j >> 12; int w = wt / 3, t = wt % 3;
        const float* Ws = w ? W52 : W51;
        WT[j] = f2bf(Ws[(o * 64 + c) * 3 + t]);
    } else if (i < 78848) {
        int j = i - 73728; int o = j >> 6, c = j & 63;
        float v = o < 8 ? Wq[o * 64 + c] : (o < 16 ? Wk[(o - 8) * 64 + c] : Wv[(o - 16) * 64 + c]);
        WQKV[j] = f2bf(v);
    } else if (i < 78928) {
        int o = i - 78848;
        BQKV[o] = o < 8 ? bq[o] : (o < 16 ? bk[o - 8] : bv[o - 16]);
    } else if (i < 79440) {
        FSUM[i - 78928] = 0.f;
    }
}

// ---- conv1x1(x) both branches in ONE pass over x; pre-BN bf16 + stats partials ----
// grid (32, B): outputs 0..63 -> Y1T [l][c], 64..127 -> Y2C [c][l]
__global__ __launch_bounds__(256) void k_conv1(const float* __restrict__ x,
        const unsigned short* __restrict__ W5BF,
        unsigned short* __restrict__ Y1T, unsigned short* __restrict__ Y2C,
        float* __restrict__ PART1) {
    __shared__ float lds_part[4][256];
    int lt = blockIdx.x, b = blockIdx.y;
    int w = threadIdx.x >> 6, lane = threadIdx.x & 63;
    int n = lane & 15, quad = lane >> 4;
    int lp = lt * 64 + w * 16 + n;          // padded output row
    int ls = lp - 1;                        // source col in x
    bool valid = (ls >= 0) && (ls < L);
    // load + convert x fragments once
    bshort8 xb[8];
#pragma unroll
    for (int ck = 0; ck < 8; ++ck) {
        bshort8 v = {};
        if (valid) {
            const float* xs = x + ((size_t)(b * C + ck * 32 + quad * 8)) * L + ls;
#pragma unroll
            for (int j = 0; j < 8; ++j)
                ((unsigned short*)&v)[j] = f2bf(xs[(size_t)j * L]);
        }
        xb[ck] = v;
    }
    f32x4 acc[8];
#pragma unroll
    for (int ot = 0; ot < 8; ++ot) {
        f32x4 a = {0.f, 0.f, 0.f, 0.f};
#pragma unroll
        for (int ck = 0; ck < 8; ++ck) {
            bshort8 wf = *(const bshort8*)(W5BF + (size_t)(ot * 16 + n) * C + ck * 32 + quad * 8);
            a = __builtin_amdgcn_mfma_f32_16x16x32_bf16(wf, xb[ck], a, 0, 0, 0);
        }
        acc[ot] = a;
    }
    // branch A (ot 0..3): Y1T [l][c] packed stores
#pragma unroll
    for (int ot = 0; ot < 4; ++ot) {
        uint2 pv;
        pv.x = pk2(acc[ot][0], acc[ot][1]);
        pv.y = pk2(acc[ot][2], acc[ot][3]);
        *(uint2*)(Y1T + ((size_t)(b * LP + lp)) * IC + ot * 16 + quad * 4) = pv;
    }
    // branch B (ot 4..7): Y2C [c][l] scalar stores
#pragma unroll
    for (int ot = 4; ot < 8; ++ot)
#pragma unroll
        for (int r = 0; r < 4; ++r) {
            int o = (ot - 4) * 16 + quad * 4 + r;
            Y2C[((size_t)(b * IC + o)) * LP + lp] = f2bf(acc[ot][r]);
        }
    // stats partials for all 128 channels
#pragma unroll
    for (int ot = 0; ot < 8; ++ot)
#pragma unroll
        for (int r = 0; r < 4; ++r) {
            float s = acc[ot][r], q = s * s;
#pragma unroll
            for (int msk = 1; msk < 16; msk <<= 1) {
                s += __shfl_xor(s, msk, 64);
                q += __shfl_xor(q, msk, 64);
            }
            if (n == 0) {
                int ch = ot * 16 + quad * 4 + r;
                lds_part[w][ch * 2] = s;
                lds_part[w][ch * 2 + 1] = q;
            }
        }
    __syncthreads();
    int t = threadIdx.x;
    float s = lds_part[0][t] + lds_part[1][t] + lds_part[2][t] + lds_part[3][t];
    PART1[(size_t)t * 256 + (b * 32 + lt)] = s;
}

// ---- reduce stats partials -> BN affine coefs (A, B) per channel ----
__global__ __launch_bounds__(256) void k_red(const float* __restrict__ PART,
        const float* __restrict__ g0, const float* __restrict__ b0,
        const float* __restrict__ g1, const float* __restrict__ b1,
        float* __restrict__ COEF) {
    int ch = blockIdx.x;   // 0..127
    int t = threadIdx.x;
    float s = PART[(size_t)(ch * 2) * 256 + t];
    float q = PART[(size_t)(ch * 2 + 1) * 256 + t];
    for (int off = 32; off; off >>= 1) {
        s += __shfl_down(s, off, 64);
        q += __shfl_down(q, off, 64);
    }
    __shared__ float rs[4], rq[4];
    if ((t & 63) == 0) { rs[t >> 6] = s; rq[t >> 6] = q; }
    __syncthreads();
    if (t == 0) {
        float S = rs[0] + rs[1] + rs[2] + rs[3];
        float Q = rq[0] + rq[1] + rq[2] + rq[3];
        float mu = S * INVN;
        float var = Q * INVN - mu * mu;
        float gv = ch < 64 ? g0[ch] : g1[ch - 64];
        float bv = ch < 64 ? b0[ch] : b1[ch - 64];
        float A = gv * rsqrtf(var + BN_EPS);
        COEF[ch * 2] = A;
        COEF[ch * 2 + 1] = bv - mu * A;
    }
}

// ---- qkv via MFMA with BN-on-the-fly from Y1T ----
__global__ __launch_bounds__(256) void k_qkv(const unsigned short* __restrict__ Y1T,
        const float* __restrict__ COEF1,
        const unsigned short* __restrict__ WQKV, const float* __restrict__ BQKV,
        unsigned short* __restrict__ QT, unsigned short* __restrict__ KT,
        unsigned short* __restrict__ VB) {
    __shared__ float cA[64], cB[64];
    int lt = blockIdx.x, b = blockIdx.y;
    int t = threadIdx.x;
    if (t < 64) { cA[t] = COEF1[t * 2]; cB[t] = COEF1[t * 2 + 1]; }
    __syncthreads();
    int w = t >> 6, lane = t & 63, n = lane & 15, quad = lane >> 4;
    int lrow = lt * 64 + w * 16 + n;
    bshort8 fb[2];
#pragma unroll
    for (int kt = 0; kt < 2; ++kt) {
        bshort8 raw = *(const bshort8*)(Y1T + ((size_t)(b * LP + lrow)) * IC + kt * 32 + quad * 8);
        bshort8 f;
#pragma unroll
        for (int j = 0; j < 8; ++j) {
            int c = kt * 32 + quad * 8 + j;
            float v = fmaf(cA[c], bf2f((unsigned short)raw[j]), cB[c]);
            v = fmaxf(v, 0.f);
            ((unsigned short*)&f)[j] = f2bf(v);
        }
        fb[kt] = f;
    }
    f32x4 acc[5];
#pragma unroll
    for (int ot = 0; ot < 5; ++ot) {
        f32x4 a = {0.f, 0.f, 0.f, 0.f};
#pragma unroll
        for (int kt = 0; kt < 2; ++kt) {
            bshort8 wf = *(const bshort8*)(WQKV + (size_t)(ot * 16 + n) * IC + kt * 32 + quad * 8);
            a = __builtin_amdgcn_mfma_f32_16x16x32_bf16(wf, fb[kt], a, 0, 0, 0);
        }
        acc[ot] = a;
    }
#pragma unroll
    for (int ot = 0; ot < 5; ++ot)
#pragma unroll
        for (int r = 0; r < 4; ++r) {
            int o = ot * 16 + quad * 4 + r;
            unsigned short bv16 = f2bf(acc[ot][r] + BQKV[o]);
            if (ot == 0) {
                if (o < 8) QT[((size_t)(b * LP + lrow)) * 8 + o] = bv16;
                else KT[((size_t)(b * LP + lrow)) * 8 + (o - 8)] = bv16;
            } else {
                VB[((size_t)(b * IC + (o - 16))) * LP + lrow] = bv16;
            }
        }
}

// ---- flash PAM without max-tracking (scores provably small); split-K x4 ----
__global__ __launch_bounds__(256) void k_pam(
        const unsigned short* __restrict__ qT, const unsigned short* __restrict__ kT,
        const unsigned short* __restrict__ vb,
        unsigned short* __restrict__ OPART, float* __restrict__ LPART) {
    __shared__ unsigned char smem[18432];
    unsigned short* vs = (unsigned short*)smem;       // [64][72]
    unsigned short* ps = vs + 4608;                   // 4 x [16][72]
    float* os = (float*)smem;                         // [64][65] aliased after loop
    int qt = blockIdx.x, ks = blockIdx.y, b = blockIdx.z;
    int l0 = qt * 64;
    int tid = threadIdx.x;
    int wq = tid >> 6, lane = tid & 63, n = lane & 15, quad = lane >> 4;
    bshort8 qa = {};
    if (quad == 0)
        qa = *(const bshort8*)(qT + ((size_t)(b * LP + l0 + wq * 16 + n)) * 8);
    f32x4 acc[4];
#pragma unroll
    for (int s = 0; s < 4; ++s) acc[s] = (f32x4){0.f, 0.f, 0.f, 0.f};
    float li[4] = {0.f, 0.f, 0.f, 0.f};
    unsigned short* pw = ps + wq * 16 * 72;

    for (int it = 0; it < 8; ++it) {
        int m0 = ks * 512 + it * 64;
        __syncthreads();
        {
            int row = tid >> 2, chn = tid & 3;
            const unsigned short* src = vb + ((size_t)(b * IC + row)) * LP + m0 + chn * 16;
            unsigned short* dstl = vs + row * 72 + chn * 16;
            *(bshort8*)dstl = *(const bshort8*)src;
            *(bshort8*)(dstl + 8) = *(const bshort8*)(src + 8);
        }
        bshort8 kb[4];
#pragma unroll
        for (int s = 0; s < 4; ++s) kb[s] = (bshort8){};
        if (quad == 0) {
#pragma unroll
            for (int s = 0; s < 4; ++s)
                kb[s] = *(const bshort8*)(kT + ((size_t)(b * LP + m0 + s * 16 + n)) * 8);
        }
        __syncthreads();
        f32x4 sc[4];
#pragma unroll
        for (int s = 0; s < 4; ++s)
            sc[s] = __builtin_amdgcn_mfma_f32_16x16x32_bf16(qa, kb[s],
                        (f32x4){0.f, 0.f, 0.f, 0.f}, 0, 0, 0);
#pragma unroll
        for (int s = 0; s < 4; ++s)
#pragma unroll
            for (int r = 0; r < 4; ++r) {
                float p = __expf(sc[s][r]);
                li[r] += p;
                pw[(quad * 4 + r) * 72 + s * 16 + n] = f2bf(p);
            }
#pragma unroll
        for (int step = 0; step < 2; ++step) {
            bshort8 pa = *(const bshort8*)(pw + n * 72 + step * 32 + quad * 8);
#pragma unroll
            for (int s = 0; s < 4; ++s) {
                bshort8 vf = *(const bshort8*)(vs + (s * 16 + n) * 72 + step * 32 + quad * 8);
                acc[s] = __builtin_amdgcn_mfma_f32_16x16x32_bf16(pa, vf, acc[s], 0, 0, 0);
            }
        }
    }
    __syncthreads();
#pragma unroll
    for (int s = 0; s < 4; ++s)
#pragma unroll
        for (int r = 0; r < 4; ++r)
            os[(s * 16 + n) * 65 + wq * 16 + quad * 4 + r] = acc[s][r];
    size_t lbase = ((size_t)((b * 32 + qt) * 4 + ks)) * 64;
#pragma unroll
    for (int r = 0; r < 4; ++r) {
        float s_ = li[r];
#pragma unroll
        for (int msk = 1; msk < 16; msk <<= 1) s_ += __shfl_xor(s_, msk, 64);
        if (n == 0) LPART[lbase + wq * 16 + quad * 4 + r] = s_;
    }
    __syncthreads();
    size_t ob = ((size_t)((b * 32 + qt) * 4 + ks)) * 4096;
    int c = tid >> 2, qc = tid & 3;
    unsigned int* od = (unsigned int*)(OPART + ob + c * 64 + qc * 16);
#pragma unroll
    for (int i = 0; i < 8; ++i)
        od[i] = pk2(os[c * 65 + qc * 16 + 2 * i], os[c * 65 + qc * 16 + 2 * i + 1]);
}

// ---- merge split-K (linear), add BN'd residual, write sa_feat^T bf16 ----
__global__ __launch_bounds__(256) void k_pam_combine(
        const unsigned short* __restrict__ OPART, const float* __restrict__ LPART,
        const unsigned short* __restrict__ Y1T, const float* __restrict__ COEF1,
        const float* __restrict__ gamma, unsigned short* __restrict__ SAFT) {
    __shared__ float dn[64];
    __shared__ float cA[64], cB[64];
    __shared__ unsigned short tile[64 * 66];
    int qt = blockIdx.x, b = blockIdx.y;
    int l0 = qt * 64;
    int t = threadIdx.x;
    if (t < 64) {
        cA[t] = COEF1[t * 2]; cB[t] = COEF1[t * 2 + 1];
        size_t lbase = ((size_t)((b * 32 + qt) * 4)) * 64;
        dn[t] = LPART[lbase + t] + LPART[lbase + 64 + t] +
                LPART[lbase + 128 + t] + LPART[lbase + 192 + t];
    }
    __syncthreads();
    int c = t >> 2, qc = t & 3;
    float O[16];
#pragma unroll
    for (int i = 0; i < 16; ++i) O[i] = 0.f;
    size_t ob = ((size_t)((b * 32 + qt) * 4)) * 4096 + c * 64 + qc * 16;
#pragma unroll
    for (int s = 0; s < 4; ++s) {
        bshort8 p0 = *(const bshort8*)(OPART + ob + (size_t)s * 4096);
        bshort8 p1 = *(const bshort8*)(OPART + ob + (size_t)s * 4096 + 8);
#pragma unroll
        for (int i = 0; i < 8; ++i) {
            O[i]     += bf2f((unsigned short)p0[i]);
            O[8 + i] += bf2f((unsigned short)p1[i]);
        }
    }
    float gm = gamma[0];
#pragma unroll
    for (int i = 0; i < 16; ++i) {
        int q = qc * 16 + i;
        unsigned short raw = Y1T[((size_t)(b * LP + l0 + q)) * IC + c];
        float f1v = fmaxf(fmaf(cA[c], bf2f(raw), cB[c]), 0.f);
        float val = fmaf(gm, O[i] / dn[q], f1v);
        tile[q * 66 + c] = f2bf(val);
    }
    __syncthreads();
    int li = t >> 2, cc = t & 3;
    unsigned int* dst = (unsigned int*)(SAFT + ((size_t)(b * LP + l0 + li)) * IC + cc * 16);
#pragma unroll
    for (int i = 0; i < 8; ++i)
        dst[i] = *(unsigned int*)(tile + li * 66 + cc * 16 + 2 * i);
}

// ---- CAM Gram via MFMA (A-frag == B-frag from Y2C rows, BN on the fly) ----
// grid (16, B); wave w covers K=32 chunk; slot = blk*4 + w (64 slots per b)
__global__ __launch_bounds__(256) void k_gram(const unsigned short* __restrict__ Y2C,
        const float* __restrict__ COEF1, float* __restrict__ EPART) {
    __shared__ float cA[64], cB[64];
    int blk = blockIdx.x, b = blockIdx.y;
    int t = threadIdx.x;
    if (t < 64) { cA[t] = COEF1[(64 + t) * 2]; cB[t] = COEF1[(64 + t) * 2 + 1]; }
    __syncthreads();
    int w = t >> 6, lane = t & 63, n = lane & 15, quad = lane >> 4;
    int lb = blk * 128 + w * 32 + quad * 8;
    bshort8 frag[4];
#pragma unroll
    for (int g = 0; g < 4; ++g) {
        int c = g * 16 + n;
        bshort8 raw = *(const bshort8*)(Y2C + ((size_t)(b * IC + c)) * LP + lb);
        bshort8 f;
        float A = cA[c], Bc = cB[c];
#pragma unroll
        for (int j = 0; j < 8; ++j)
            ((unsigned short*)&f)[j] = f2bf(fmaxf(fmaf(A, bf2f((unsigned short)raw[j]), Bc), 0.f));
        frag[g] = f;
    }
    f32x4 acc[4][4];
#pragma unroll
    for (int ti = 0; ti < 4; ++ti)
#pragma unroll
        for (int tj = 0; tj < 4; ++tj)
            acc[ti][tj] = __builtin_amdgcn_mfma_f32_16x16x32_bf16(frag[ti], frag[tj],
                              (f32x4){0.f, 0.f, 0.f, 0.f}, 0, 0, 0);
    float* ep = EPART + ((size_t)(b * 64 + blk * 4 + w)) * 4096;
#pragma unroll
    for (int ti = 0; ti < 4; ++ti)
#pragma unroll
        for (int tj = 0; tj < 4; ++tj)
#pragma unroll
            for (int r = 0; r < 4; ++r)
                ep[(ti * 16 + quad * 4 + r) * 64 + tj * 16 + n] = acc[ti][tj][r];
}

__global__ __launch_bounds__(256) void k_cam_softmax(const float* __restrict__ EPART,
        float* __restrict__ attn) {
    __shared__ float e[4096];
    int b = blockIdx.x, t = threadIdx.x;
    for (int idx = t; idx < 4096; idx += 256) {
        float s = 0.f;
        for (int ch = 0; ch < 64; ++ch) s += EPART[((size_t)(b * 64 + ch)) * 4096 + idx];
        e[idx] = s;
    }
    __syncthreads();
    if (t < 64) {
        float mn = INFINITY;
        for (int d = 0; d < 64; ++d) mn = fminf(mn, e[t * 64 + d]);
        float s = 0.f;
        float* a = attn + (size_t)b * 4096 + t * 64;
        for (int d = 0; d < 64; ++d) { float p = __expf(mn - e[t * 64 + d]); a[d] = p; s += p; }
        float inv = 1.f / s;
        for (int d = 0; d < 64; ++d) a[d] *= inv;
    }
}

// ---- CAM apply with BN-on-the-fly; writes sc_feat^T bf16 ----
__global__ __launch_bounds__(256) void k_cam_apply(const float* __restrict__ attn,
        const unsigned short* __restrict__ Y2C, const float* __restrict__ COEF1,
        const float* __restrict__ gamma, unsigned short* __restrict__ SCFT) {
    __shared__ __align__(16) float as[64 * 64];
    __shared__ float cA[64], cB[64];
    __shared__ unsigned short tile[128 * 66];
    int b = blockIdx.y;
    int l0 = blockIdx.x * 128;
    int t = threadIdx.x;
    int lq = t & 127, ch = t >> 7;
    if (t < 64) { cA[t] = COEF1[(64 + t) * 2]; cB[t] = COEF1[(64 + t) * 2 + 1]; }
    for (int i = t; i < 4096; i += 256) as[i] = attn[(size_t)b * 4096 + i];
    __syncthreads();
    float acc[32];
#pragma unroll
    for (int i = 0; i < 32; ++i) acc[i] = 0.f;
    const unsigned short* fb = Y2C + (size_t)b * IC * LP + l0 + lq;
    for (int d4 = 0; d4 < 16; ++d4) {
        float fv[4];
#pragma unroll
        for (int i = 0; i < 4; ++i) {
            int d = 4 * d4 + i;
            fv[i] = fmaxf(fmaf(cA[d], bf2f(fb[(size_t)d * LP]), cB[d]), 0.f);
        }
#pragma unroll
        for (int cc = 0; cc < 32; ++cc) {
            const float4 a4 = *reinterpret_cast<const float4*>(as + (ch * 32 + cc) * 64 + d4 * 4);
            acc[cc] += a4.x * fv[0] + a4.y * fv[1] + a4.z * fv[2] + a4.w * fv[3];
        }
    }
    float gm = gamma[0];
#pragma unroll
    for (int cc = 0; cc < 32; ++cc) {
        int c = ch * 32 + cc;
        float res = fmaxf(fmaf(cA[c], bf2f(fb[(size_t)c * LP]), cB[c]), 0.f);
        tile[lq * 66 + c] = f2bf(fmaf(gm, acc[cc], res));
    }
    __syncthreads();
    int li = t >> 1, half = t & 1;
    unsigned int* dst = (unsigned int*)(SCFT + ((size_t)(b * LP + l0 + li)) * IC + half * 32);
#pragma unroll
    for (int i = 0; i < 16; ++i)
        dst[i] = *(unsigned int*)(tile + li * 66 + half * 32 + 2 * i);
}

// ---- conv3 (both branches, og picks) -> pre-BN bf16 + stats partials ----
__global__ __launch_bounds__(256) void k_conv3(const unsigned short* __restrict__ SAFT,
        const unsigned short* __restrict__ SCFT, const unsigned short* __restrict__ WTall,
        unsigned short* __restrict__ Y51T, unsigned short* __restrict__ Y52T,
        float* __restrict__ PART2) {
    __shared__ float lds_part[4][128];
    int lt = blockIdx.x, og = blockIdx.y, b = blockIdx.z;
    const unsigned short* FTsrc = og ? SCFT : SAFT;
    const unsigned short* WT = WTall + og * 12288;
    unsigned short* dst = og ? Y52T : Y51T;
    int l0 = lt * 64;
    int w = threadIdx.x >> 6, lane = threadIdx.x & 63, n = lane & 15, quad = lane >> 4;
    int lrow = l0 + w * 16 + n;
    f32x4 acc[4];
#pragma unroll
    for (int ot = 0; ot < 4; ++ot) acc[ot] = (f32x4){0.f, 0.f, 0.f, 0.f};
#pragma unroll
    for (int t3 = 0; t3 < 3; ++t3) {
        int row = lrow + t3 - 1;
        bshort8 fb[2];
#pragma unroll
        for (int kt = 0; kt < 2; ++kt) {
            if (row >= 0 && row < LP)
                fb[kt] = *(const bshort8*)(FTsrc + ((size_t)(b * LP + row)) * IC + kt * 32 + quad * 8);
            else fb[kt] = (bshort8){};
        }
#pragma unroll
        for (int ot = 0; ot < 4; ++ot)
#pragma unroll
            for (int kt = 0; kt < 2; ++kt) {
                bshort8 wf = *(const bshort8*)(WT + ((size_t)(t3 * 64 + ot * 16 + n)) * IC + kt * 32 + quad * 8);
                acc[ot] = __builtin_amdgcn_mfma_f32_16x16x32_bf16(wf, fb[kt], acc[ot], 0, 0, 0);
            }
    }
#pragma unroll
    for (int ot = 0; ot < 4; ++ot) {
        uint2 pv;
        pv.x = pk2(acc[ot][0], acc[ot][1]);
        pv.y = pk2(acc[ot][2], acc[ot][3]);
        *(uint2*)(dst + ((size_t)(b * LP + lrow)) * IC + ot * 16 + quad * 4) = pv;
    }
#pragma unroll
    for (int ot = 0; ot < 4; ++ot)
#pragma unroll
        for (int r = 0; r < 4; ++r) {
            float s = acc[ot][r], q = s * s;
#pragma unroll
            for (int msk = 1; msk < 16; msk <<= 1) {
                s += __shfl_xor(s, msk, 64);
                q += __shfl_xor(q, msk, 64);
            }
            if (n == 0) {
                int cch = ot * 16 + quad * 4 + r;
                lds_part[w][cch * 2] = s;
                lds_part[w][cch * 2 + 1] = q;
            }
        }
    __syncthreads();
    int t = threadIdx.x;
    if (t < 128) {
        float s = lds_part[0][t] + lds_part[1][t] + lds_part[2][t] + lds_part[3][t];
        PART2[(size_t)(og * 128 + t) * 256 + (b * 32 + lt)] = s;
    }
}

// ---- final conv1x1 pair, BN-on-the-fly inputs, + fused channel sums for sasc ----
__global__ __launch_bounds__(256) void k_final(const unsigned short* __restrict__ Y51T,
        const unsigned short* __restrict__ Y52T, const float* __restrict__ COEF2,
        const unsigned short* __restrict__ W67,
        const float* __restrict__ b6, const float* __restrict__ b7,
        float* __restrict__ out_sa, float* __restrict__ out_sc,
        float* __restrict__ FSUM) {
    __shared__ float cA[128], cB[128];
    __shared__ float fsw[4][64];
    int lt = blockIdx.x, og = blockIdx.y, b = blockIdx.z;
    int t = threadIdx.x;
    if (t < 128) { cA[t] = COEF2[t * 2]; cB[t] = COEF2[t * 2 + 1]; }
    __syncthreads();
    int w = t >> 6, lane = t & 63, n = lane & 15, quad = lane >> 4;
    int lrow = lt * 64 + w * 16 + n;
    float fs_lane[16];
    bshort8 ba[2], bb[2];
#pragma unroll
    for (int kt = 0; kt < 2; ++kt) {
        bshort8 ra = *(const bshort8*)(Y51T + ((size_t)(b * LP + lrow)) * IC + kt * 32 + quad * 8);
        bshort8 rb = *(const bshort8*)(Y52T + ((size_t)(b * LP + lrow)) * IC + kt * 32 + quad * 8);
        bshort8 fa, fb;
#pragma unroll
        for (int j = 0; j < 8; ++j) {
            int c = kt * 32 + quad * 8 + j;
            float v1 = fmaxf(fmaf(cA[c], bf2f((unsigned short)ra[j]), cB[c]), 0.f);
            float v2 = fmaxf(fmaf(cA[64 + c], bf2f((unsigned short)rb[j]), cB[64 + c]), 0.f);
            ((unsigned short*)&fa)[j] = f2bf(v1);
            ((unsigned short*)&fb)[j] = f2bf(v2);
            fs_lane[kt * 8 + j] = v1 + v2;
        }
        ba[kt] = fa; bb[kt] = fb;
    }
    f32x4 accA[4], accB[4];
#pragma unroll
    for (int ot = 0; ot < 4; ++ot) {
        accA[ot] = (f32x4){0.f, 0.f, 0.f, 0.f};
        accB[ot] = (f32x4){0.f, 0.f, 0.f, 0.f};
    }
#pragma unroll
    for (int ot = 0; ot < 4; ++ot)
#pragma unroll
        for (int kt = 0; kt < 2; ++kt) {
            bshort8 wa = *(const bshort8*)(W67 + (size_t)(og * 64 + ot * 16 + n) * IC + kt * 32 + quad * 8);
            bshort8 wb = *(const bshort8*)(W67 + 8192 + (size_t)(og * 64 + ot * 16 + n) * IC + kt * 32 + quad * 8);
            accA[ot] = __builtin_amdgcn_mfma_f32_16x16x32_bf16(wa, ba[kt], accA[ot], 0, 0, 0);
            accB[ot] = __builtin_amdgcn_mfma_f32_16x16x32_bf16(wb, bb[kt], accB[ot], 0, 0, 0);
        }
#pragma unroll
    for (int ot = 0; ot < 4; ++ot)
#pragma unroll
        for (int r = 0; r < 4; ++r) {
            int o = og * 64 + ot * 16 + quad * 4 + r;
            out_sa[((size_t)(b * OC + o)) * LP + lrow] = accA[ot][r] + b6[o];
            out_sc[((size_t)(b * OC + o)) * LP + lrow] = accB[ot][r] + b7[o];
        }
    if (og == 0) {
#pragma unroll
        for (int i = 0; i < 16; ++i) {
            float s = fs_lane[i];
#pragma unroll
            for (int msk = 1; msk < 16; msk <<= 1) s += __shfl_xor(s, msk, 64);
            if (n == 0) {
                int c = (i >> 3) * 32 + quad * 8 + (i & 7);
                fsw[w][c] = s;
            }
        }
        __syncthreads();
        if (t < 64)
            atomicAdd(&FSUM[b * 64 + t], fsw[0][t] + fsw[1][t] + fsw[2][t] + fsw[3][t]);
    }
}

// ---- sasc = W8 @ mean(sa_conv+sc_conv) + b8 ----
__global__ __launch_bounds__(128) void k_sasc(const float* __restrict__ FSUM,
        const float* __restrict__ W8, const float* __restrict__ b8,
        float* __restrict__ out) {
    __shared__ float mean[64];
    int b = blockIdx.x, t = threadIdx.x;
    if (t < 64) mean[t] = FSUM[b * 64 + t] * (1.f / (float)LP);
    __syncthreads();
    float s = b8[t];
    for (int c = 0; c < 64; ++c) s = fmaf(W8[t * 64 + c], mean[c], s);
    out[b * OC + t] = s;
}

extern "C" void kernel_launch(void* const* d_in, const int* in_sizes, int n_in,
                              void* d_out, int out_size, void* d_ws, size_t ws_size,
                              hipStream_t stream) {
    (void)in_sizes; (void)n_in; (void)out_size; (void)ws_size;
    const float* x    = (const float*)d_in[0];
    const float* W5a  = (const float*)d_in[1];
    const float* g5a  = (const float*)d_in[2];
    const float* b5a  = (const float*)d_in[3];
    const float* W5c  = (const float*)d_in[4];
    const float* g5c  = (const float*)d_in[5];
    const float* b5c  = (const float*)d_in[6];
    const float* Wq   = (const float*)d_in[7];
    const float* bq   = (const float*)d_in[8];
    const float* Wk   = (const float*)d_in[9];
    const float* bk   = (const float*)d_in[10];
    const float* Wv   = (const float*)d_in[11];
    const float* bv   = (const float*)d_in[12];
    const float* gpam = (const float*)d_in[13];
    const float* gcam = (const float*)d_in[14];
    const float* W51  = (const float*)d_in[15];
    const float* g51  = (const float*)d_in[16];
    const float* b51  = (const float*)d_in[17];
    const float* W52  = (const float*)d_in[18];
    const float* g52  = (const float*)d_in[19];
    const float* b52  = (const float*)d_in[20];
    const float* W6   = (const float*)d_in[21];
    const float* b6   = (const float*)d_in[22];
    const float* W7   = (const float*)d_in[23];
    const float* b7   = (const float*)d_in[24];
    const float* W8   = (const float*)d_in[25];
    const float* b8   = (const float*)d_in[26];

    float* ws = (float*)d_ws;
    float* out = (float*)d_out;
    unsigned short* Y1T  = (unsigned short*)(ws + OFF_Y1T);
    unsigned short* Y2C  = (unsigned short*)(ws + OFF_Y2C);
    unsigned short* SAFT = (unsigned short*)(ws + OFF_SAFT);
    unsigned short* SCFT = (unsigned short*)(ws + OFF_SCFT);
    unsigned short* Y51T = (unsigned short*)(ws + OFF_Y51T);
    unsigned short* Y52T = (unsigned short*)(ws + OFF_Y52T);
    unsigned short* VB   = (unsigned short*)(ws + OFF_VB);
    unsigned short* QT   = (unsigned short*)(ws + OFF_QT);
    unsigned short* KT   = (unsigned short*)(ws + OFF_KT);
    float* LPART  = ws + OFF_LPART;
    float* EPART  = ws + OFF_EPART;
    float* ATTN   = ws + OFF_ATTN;
    float* PART1  = ws + OFF_PART1;
    float* PART2  = ws + OFF_PART2;
    float* COEF1  = ws + OFF_COEF1;
    float* COEF2  = ws + OFF_COEF2;
    float* FSUM   = ws + OFF_FSUM;
    unsigned short* W5BF = (unsigned short*)(ws + OFF_W5BF);
    unsigned short* W67  = (unsigned short*)(ws + OFF_W67);
    unsigned short* WT   = (unsigned short*)(ws + OFF_WT);
    unsigned short* WQKV = (unsigned short*)(ws + OFF_WQKV);
    float* BQKV = ws + OFF_BQKV;

    float* out_sa = out + B * OC;
    float* out_sc = out + B * OC + (size_t)B * OC * LP;
    unsigned short* OPART = (unsigned short*)out_sa;  // scratch, overwritten by k_final

    k_wprep<<<311, 256, 0, stream>>>(W5a, W5c, W6, W7, W51, W52, Wq, Wk, Wv,
                                     bq, bk, bv, W5BF, W67, WT, WQKV, BQKV, FSUM);
    k_conv1<<<dim3(32, B), 256, 0, stream>>>(x, W5BF, Y1T, Y2C, PART1);
    k_red<<<128, 256, 0, stream>>>(PART1, g5a, b5a, g5c, b5c, COEF1);
    k_qkv<<<dim3(32, B), 256, 0, stream>>>(Y1T, COEF1, WQKV, BQKV, QT, KT, VB);
    k_pam<<<dim3(32, 4, B), 256, 0, stream>>>(QT, KT, VB, OPART, LPART);
    k_pam_combine<<<dim3(32, B), 256, 0, stream>>>(OPART, LPART, Y1T, COEF1, gpam, SAFT);
    k_gram<<<dim3(16, B), 256, 0, stream>>>(Y2C, COEF1, EPART);
    k_cam_softmax<<<B, 256, 0, stream>>>(EPART, ATTN);
    k_cam_apply<<<dim3(16, B), 256, 0, stream>>>(ATTN, Y2C, COEF1, gcam, SCFT);
    k_conv3<<<dim3(32, 2, B), 256, 0, stream>>>(SAFT, SCFT, WT, Y51T, Y52T, PART2);
    k_red<<<128, 256, 0, stream>>>(PART2, g51, b51, g52, b52, COEF2);
    k_final<<<dim3(32, 2, B), 256, 0, stream>>>(Y51T, Y52T, COEF2, W67, b6, b7,
                                                out_sa, out_sc, FSUM);
    k_sasc<<<B, 128, 0, stream>>>(FSUM, W8, b8, out);
}

// Round 6
// 233.459 us; speedup vs baseline: 1.1136x; 1.1136x over previous
//
#include <hip/hip_runtime.h>
#include <math.h>

#define B 8
#define C 256
#define L 2046
#define LP 2048
#define IC 64
#define OC 128
#define BN_EPS 1e-5f
#define INVN (1.f / 16384.f)   // 1/(B*LP)

// ws offsets (float units)
#define OFF_Y1T    0u          // conv1 out (pre-BN) bf16 [b][l][64]
#define OFF_Y2C    524288u     // conv1 out (pre-BN) bf16 [b][64][l]
#define OFF_SAFT   1048576u    // sa_feat bf16 [b][l][64]
#define OFF_SCFT   1572864u    // sc_feat bf16 [b][l][64]
#define OFF_Y51T   2097152u    // conv3 out (pre-BN) bf16 [b][l][64]
#define OFF_Y52T   2621440u
#define OFF_VB     3145728u    // v bf16 [b][64][l]
#define OFF_QT     3670016u    // q bf16 [b][l][8]
#define OFF_KT     3735552u
#define OFF_LPART  3801088u    // pam denominators [b][32][4][64]
#define OFF_EPART  3866624u    // CAM gram partials [b][16][64][64]
#define OFF_ATTN   4390912u
#define OFF_STATS1 4423680u    // [128ch][2] atomic sum/sumsq
#define OFF_STATS2 4423936u
#define OFF_W5BF   4424192u    // bf16 [128][256]
#define OFF_W67    4440576u    // bf16 [2][128][64]
#define OFF_WT     4448768u    // bf16 [2][3][64][64]
#define OFF_WQKV   4461056u    // bf16 [80][64]
#define OFF_BQKV   4463616u    // fp32 [80]

typedef __attribute__((ext_vector_type(8))) short bshort8;
typedef __attribute__((ext_vector_type(4))) float f32x4;

__device__ __forceinline__ unsigned short f2bf(float f) {
    union { float f; unsigned int u; } v; v.f = f;
    unsigned int r = v.u + 0x7fffu + ((v.u >> 16) & 1u);
    return (unsigned short)(r >> 16);
}
__device__ __forceinline__ float bf2f(unsigned short u) {
    union { unsigned int i; float f; } v; v.i = ((unsigned int)u) << 16;
    return v.f;
}
__device__ __forceinline__ unsigned int pk2(float a, float b) {
    return (unsigned int)f2bf(a) | ((unsigned int)f2bf(b) << 16);
}

// load BN affine coefs for [base..base+cnt) channels from atomic stats into LDS
__device__ __forceinline__ void load_coef(const float* __restrict__ STATS,
        const float* __restrict__ g, const float* __restrict__ beta,
        int base, int cnt, float* cA, float* cB) {
    int t = threadIdx.x;
    if (t < cnt) {
        float s = STATS[(base + t) * 2], q = STATS[(base + t) * 2 + 1];
        float mu = s * INVN;
        float var = q * INVN - mu * mu;
        float A = g[t] * rsqrtf(var + BN_EPS);
        cA[t] = A;
        cB[t] = beta[t] - mu * A;
    }
}

// ---- weight prep + stats zero + out b8-init ----
__global__ __launch_bounds__(256) void k_wprep(
        const float* __restrict__ W5a, const float* __restrict__ W5c,
        const float* __restrict__ W6, const float* __restrict__ W7,
        const float* __restrict__ W51, const float* __restrict__ W52,
        const float* __restrict__ Wq, const float* __restrict__ Wk,
        const float* __restrict__ Wv, const float* __restrict__ bq,
        const float* __restrict__ bk, const float* __restrict__ bv,
        const float* __restrict__ b8,
        unsigned short* __restrict__ W5BF, unsigned short* __restrict__ W67,
        unsigned short* __restrict__ WT, unsigned short* __restrict__ WQKV,
        float* __restrict__ BQKV, float* __restrict__ STATS1,
        float* __restrict__ STATS2, float* __restrict__ out_sasc) {
    int i = blockIdx.x * 256 + threadIdx.x;
    if (i < 32768) {
        int o = i >> 8, c = i & 255;
        W5BF[i] = f2bf(o < 64 ? W5a[o * 256 + c] : W5c[(o - 64) * 256 + c]);
    } else if (i < 49152) {
        int j = i - 32768; int g = j >> 13; int r = j & 8191;
        W67[j] = f2bf(g ? W7[r] : W6[r]);
    } else if (i < 73728) {
        int j = i - 49152;
        int c = j & 63, o = (j >> 6) & 63, wt = j >> 12; int w = wt / 3, t = wt % 3;
        const float* Ws = w ? W52 : W51;
        WT[j] = f2bf(Ws[(o * 64 + c) * 3 + t]);
    } else if (i < 78848) {
        int j = i - 73728; int o = j >> 6, c = j & 63;
        float v = o < 8 ? Wq[o * 64 + c] : (o < 16 ? Wk[(o - 8) * 64 + c] : Wv[(o - 16) * 64 + c]);
        WQKV[j] = f2bf(v);
    } else if (i < 78928) {
        int o = i - 73728 - 5120;
        BQKV[o] = o < 8 ? bq[o] : (o < 16 ? bk[o - 8] : bv[o - 16]);
    } else if (i < 79440) {
        int j = i - 78928;
        if (j < 256) STATS1[j] = 0.f; else STATS2[j - 256] = 0.f;
    } else if (i < 80464) {
        int j = i - 79440;
        out_sasc[j] = b8[j & 127];
    }
}

// ---- conv1x1(x) via MFMA (round-4 structure); pre-BN bf16 + atomic stats ----
// grid (32, 2, B); og=0 -> Y1T [l][c] (ch 0..63), og=1 -> Y2C [c][l] (ch 64..127)
__global__ __launch_bounds__(256) void k_conv1(const float* __restrict__ x,
        const unsigned short* __restrict__ W5BF,
        unsigned short* __restrict__ Y1T, unsigned short* __restrict__ Y2C,
        float* __restrict__ STATS1) {
    __shared__ float lds_part[4][128];
    int lt = blockIdx.x, og = blockIdx.y, b = blockIdx.z;
    int w = threadIdx.x >> 6, lane = threadIdx.x & 63;
    int n = lane & 15, quad = lane >> 4;
    int lp = lt * 64 + w * 16 + n;          // padded output row
    int ls = lp - 1;                        // source col in x
    bool valid = (ls >= 0) && (ls < L);
    f32x4 acc[4];
#pragma unroll
    for (int ot = 0; ot < 4; ++ot) acc[ot] = (f32x4){0.f, 0.f, 0.f, 0.f};
    for (int ck = 0; ck < 8; ++ck) {
        int c0 = ck * 32 + quad * 8;
        bshort8 xb = {};
        if (valid) {
            const float* xs = x + ((size_t)(b * C + c0)) * L + ls;
#pragma unroll
            for (int j = 0; j < 8; ++j)
                ((unsigned short*)&xb)[j] = f2bf(xs[(size_t)j * L]);
        }
#pragma unroll
        for (int ot = 0; ot < 4; ++ot) {
            bshort8 wf = *(const bshort8*)(W5BF + (size_t)(og * 64 + ot * 16 + n) * C + ck * 32 + quad * 8);
            acc[ot] = __builtin_amdgcn_mfma_f32_16x16x32_bf16(wf, xb, acc[ot], 0, 0, 0);
        }
    }
    if (og == 0) {
#pragma unroll
        for (int ot = 0; ot < 4; ++ot) {
            uint2 pv;
            pv.x = pk2(acc[ot][0], acc[ot][1]);
            pv.y = pk2(acc[ot][2], acc[ot][3]);
            *(uint2*)(Y1T + ((size_t)(b * LP + lp)) * IC + ot * 16 + quad * 4) = pv;
        }
    } else {
#pragma unroll
        for (int ot = 0; ot < 4; ++ot)
#pragma unroll
            for (int r = 0; r < 4; ++r) {
                int o = ot * 16 + quad * 4 + r;
                Y2C[((size_t)(b * IC + o)) * LP + lp] = f2bf(acc[ot][r]);
            }
    }
#pragma unroll
    for (int ot = 0; ot < 4; ++ot)
#pragma unroll
        for (int r = 0; r < 4; ++r) {
            float s = acc[ot][r], q = s * s;
#pragma unroll
            for (int msk = 1; msk < 16; msk <<= 1) {
                s += __shfl_xor(s, msk, 64);
                q += __shfl_xor(q, msk, 64);
            }
            if (n == 0) {
                int ch = ot * 16 + quad * 4 + r;
                lds_part[w][ch * 2] = s;
                lds_part[w][ch * 2 + 1] = q;
            }
        }
    __syncthreads();
    int t = threadIdx.x;
    if (t < 128) {
        float s = lds_part[0][t] + lds_part[1][t] + lds_part[2][t] + lds_part[3][t];
        atomicAdd(&STATS1[og * 128 + t], s);
    }
}

// ================= fuse1: qkv (256 blocks) | gram (32 blocks) =================
__device__ void role_qkv(char* dynsm, int lt, int b,
        const unsigned short* __restrict__ Y1T, const float* __restrict__ STATS1,
        const float* __restrict__ g5a, const float* __restrict__ b5a,
        const unsigned short* __restrict__ WQKV, const float* __restrict__ BQKV,
        unsigned short* __restrict__ QT, unsigned short* __restrict__ KT,
        unsigned short* __restrict__ VB) {
    float* cA = (float*)dynsm;
    float* cB = cA + 64;
    load_coef(STATS1, g5a, b5a, 0, 64, cA, cB);
    __syncthreads();
    int t = threadIdx.x;
    int w = t >> 6, lane = t & 63, n = lane & 15, quad = lane >> 4;
    int lrow = lt * 64 + w * 16 + n;
    bshort8 fb[2];
#pragma unroll
    for (int kt = 0; kt < 2; ++kt) {
        bshort8 raw = *(const bshort8*)(Y1T + ((size_t)(b * LP + lrow)) * IC + kt * 32 + quad * 8);
        bshort8 f;
#pragma unroll
        for (int j = 0; j < 8; ++j) {
            int c = kt * 32 + quad * 8 + j;
            float v = fmaxf(fmaf(cA[c], bf2f((unsigned short)raw[j]), cB[c]), 0.f);
            ((unsigned short*)&f)[j] = f2bf(v);
        }
        fb[kt] = f;
    }
    f32x4 acc[5];
#pragma unroll
    for (int ot = 0; ot < 5; ++ot) {
        f32x4 a = {0.f, 0.f, 0.f, 0.f};
#pragma unroll
        for (int kt = 0; kt < 2; ++kt) {
            bshort8 wf = *(const bshort8*)(WQKV + (size_t)(ot * 16 + n) * IC + kt * 32 + quad * 8);
            a = __builtin_amdgcn_mfma_f32_16x16x32_bf16(wf, fb[kt], a, 0, 0, 0);
        }
        acc[ot] = a;
    }
#pragma unroll
    for (int ot = 0; ot < 5; ++ot)
#pragma unroll
        for (int r = 0; r < 4; ++r) {
            int o = ot * 16 + quad * 4 + r;
            unsigned short bv16 = f2bf(acc[ot][r] + BQKV[o]);
            if (ot == 0) {
                if (o < 8) QT[((size_t)(b * LP + lrow)) * 8 + o] = bv16;
                else KT[((size_t)(b * LP + lrow)) * 8 + (o - 8)] = bv16;
            } else {
                VB[((size_t)(b * IC + (o - 16))) * LP + lrow] = bv16;
            }
        }
}

__device__ void role_gram(char* dynsm, int blk, int b,
        const unsigned short* __restrict__ Y2C, const float* __restrict__ STATS1,
        const float* __restrict__ g5c, const float* __restrict__ b5c,
        float* __restrict__ EPART) {
    float* cA = (float*)dynsm;
    float* cB = cA + 64;
    load_coef(STATS1, g5c, b5c, 64, 64, cA, cB);
    __syncthreads();
    int t = threadIdx.x;
    int w = t >> 6, lane = t & 63, n = lane & 15, quad = lane >> 4;
    f32x4 acc[4][4];
#pragma unroll
    for (int ti = 0; ti < 4; ++ti)
#pragma unroll
        for (int tj = 0; tj < 4; ++tj) acc[ti][tj] = (f32x4){0.f, 0.f, 0.f, 0.f};
    for (int chunk = 0; chunk < 4; ++chunk) {
        int lb = (blk * 4 + w) * 128 + chunk * 32 + quad * 8;
        bshort8 frag[4];
#pragma unroll
        for (int g = 0; g < 4; ++g) {
            int c = g * 16 + n;
            bshort8 raw = *(const bshort8*)(Y2C + ((size_t)(b * IC + c)) * LP + lb);
            bshort8 f;
            float A = cA[c], Bc = cB[c];
#pragma unroll
            for (int j = 0; j < 8; ++j)
                ((unsigned short*)&f)[j] = f2bf(fmaxf(fmaf(A, bf2f((unsigned short)raw[j]), Bc), 0.f));
            frag[g] = f;
        }
#pragma unroll
        for (int ti = 0; ti < 4; ++ti)
#pragma unroll
            for (int tj = 0; tj < 4; ++tj)
                acc[ti][tj] = __builtin_amdgcn_mfma_f32_16x16x32_bf16(frag[ti], frag[tj], acc[ti][tj], 0, 0, 0);
    }
    float* ep = EPART + ((size_t)(b * 16 + blk * 4 + w)) * 4096;
#pragma unroll
    for (int ti = 0; ti < 4; ++ti)
#pragma unroll
        for (int tj = 0; tj < 4; ++tj)
#pragma unroll
            for (int r = 0; r < 4; ++r)
                ep[(ti * 16 + quad * 4 + r) * 64 + tj * 16 + n] = acc[ti][tj][r];
}

__global__ __launch_bounds__(256) void k_fuse1(
        const unsigned short* __restrict__ Y1T, const unsigned short* __restrict__ Y2C,
        const float* __restrict__ STATS1,
        const float* __restrict__ g5a, const float* __restrict__ b5a,
        const float* __restrict__ g5c, const float* __restrict__ b5c,
        const unsigned short* __restrict__ WQKV, const float* __restrict__ BQKV,
        unsigned short* __restrict__ QT, unsigned short* __restrict__ KT,
        unsigned short* __restrict__ VB, float* __restrict__ EPART) {
    extern __shared__ char dynsm[];
    int idx = blockIdx.x;
    if (idx < 256) role_qkv(dynsm, idx & 31, idx >> 5, Y1T, STATS1, g5a, b5a,
                            WQKV, BQKV, QT, KT, VB);
    else { int g = idx - 256; role_gram(dynsm, g & 3, g >> 2, Y2C, STATS1, g5c, b5c, EPART); }
}

// ================= fuse2: pam (1024 blocks) | cam_softmax (8) =================
__device__ void role_pam(char* dynsm, int qt, int ks, int b,
        const unsigned short* __restrict__ qT, const unsigned short* __restrict__ kT,
        const unsigned short* __restrict__ vb,
        unsigned short* __restrict__ OPART, float* __restrict__ LPART) {
    unsigned short* vs = (unsigned short*)dynsm;      // [64][72]
    unsigned short* ps = vs + 4608;                   // 4 x [16][72]
    float* os = (float*)dynsm;                        // [64][65] aliased after loop
    int l0 = qt * 64;
    int tid = threadIdx.x;
    int wq = tid >> 6, lane = tid & 63, n = lane & 15, quad = lane >> 4;
    bshort8 qa = {};
    if (quad == 0)
        qa = *(const bshort8*)(qT + ((size_t)(b * LP + l0 + wq * 16 + n)) * 8);
    f32x4 acc[4];
#pragma unroll
    for (int s = 0; s < 4; ++s) acc[s] = (f32x4){0.f, 0.f, 0.f, 0.f};
    float li[4] = {0.f, 0.f, 0.f, 0.f};
    unsigned short* pw = ps + wq * 16 * 72;

    for (int it = 0; it < 8; ++it) {
        int m0 = ks * 512 + it * 64;
        __syncthreads();
        {
            int row = tid >> 2, chn = tid & 3;
            const unsigned short* src = vb + ((size_t)(b * IC + row)) * LP + m0 + chn * 16;
            unsigned short* dstl = vs + row * 72 + chn * 16;
            *(bshort8*)dstl = *(const bshort8*)src;
            *(bshort8*)(dstl + 8) = *(const bshort8*)(src + 8);
        }
        bshort8 kb[4];
#pragma unroll
        for (int s = 0; s < 4; ++s) kb[s] = (bshort8){};
        if (quad == 0) {
#pragma unroll
            for (int s = 0; s < 4; ++s)
                kb[s] = *(const bshort8*)(kT + ((size_t)(b * LP + m0 + s * 16 + n)) * 8);
        }
        __syncthreads();
        f32x4 sc[4];
#pragma unroll
        for (int s = 0; s < 4; ++s)
            sc[s] = __builtin_amdgcn_mfma_f32_16x16x32_bf16(qa, kb[s],
                        (f32x4){0.f, 0.f, 0.f, 0.f}, 0, 0, 0);
#pragma unroll
        for (int s = 0; s < 4; ++s)
#pragma unroll
            for (int r = 0; r < 4; ++r) {
                float p = __expf(sc[s][r]);
                li[r] += p;
                pw[(quad * 4 + r) * 72 + s * 16 + n] = f2bf(p);
            }
#pragma unroll
        for (int step = 0; step < 2; ++step) {
            bshort8 pa = *(const bshort8*)(pw + n * 72 + step * 32 + quad * 8);
#pragma unroll
            for (int s = 0; s < 4; ++s) {
                bshort8 vf = *(const bshort8*)(vs + (s * 16 + n) * 72 + step * 32 + quad * 8);
                acc[s] = __builtin_amdgcn_mfma_f32_16x16x32_bf16(pa, vf, acc[s], 0, 0, 0);
            }
        }
    }
    __syncthreads();
#pragma unroll
    for (int s = 0; s < 4; ++s)
#pragma unroll
        for (int r = 0; r < 4; ++r)
            os[(s * 16 + n) * 65 + wq * 16 + quad * 4 + r] = acc[s][r];
    size_t lbase = ((size_t)((b * 32 + qt) * 4 + ks)) * 64;
#pragma unroll
    for (int r = 0; r < 4; ++r) {
        float s_ = li[r];
#pragma unroll
        for (int msk = 1; msk < 16; msk <<= 1) s_ += __shfl_xor(s_, msk, 64);
        if (n == 0) LPART[lbase + wq * 16 + quad * 4 + r] = s_;
    }
    __syncthreads();
    size_t ob = ((size_t)((b * 32 + qt) * 4 + ks)) * 4096;
    int c = tid >> 2, qc = tid & 3;
    unsigned int* od = (unsigned int*)(OPART + ob + c * 64 + qc * 16);
#pragma unroll
    for (int i = 0; i < 8; ++i)
        od[i] = pk2(os[c * 65 + qc * 16 + 2 * i], os[c * 65 + qc * 16 + 2 * i + 1]);
}

__device__ void role_cam_softmax(char* dynsm, int b,
        const float* __restrict__ EPART, float* __restrict__ attn) {
    float* e = (float*)dynsm;
    int t = threadIdx.x;
    for (int idx = t; idx < 4096; idx += 256) {
        float s = 0.f;
        for (int ch = 0; ch < 16; ++ch) s += EPART[((size_t)(b * 16 + ch)) * 4096 + idx];
        e[idx] = s;
    }
    __syncthreads();
    if (t < 64) {
        float mn = INFINITY;
        for (int d = 0; d < 64; ++d) mn = fminf(mn, e[t * 64 + d]);
        float s = 0.f;
        float* a = attn + (size_t)b * 4096 + t * 64;
        for (int d = 0; d < 64; ++d) { float p = __expf(mn - e[t * 64 + d]); a[d] = p; s += p; }
        float inv = 1.f / s;
        for (int d = 0; d < 64; ++d) a[d] *= inv;
    }
}

__global__ __launch_bounds__(256) void k_fuse2(
        const unsigned short* __restrict__ QT, const unsigned short* __restrict__ KT,
        const unsigned short* __restrict__ VB,
        unsigned short* __restrict__ OPART, float* __restrict__ LPART,
        const float* __restrict__ EPART, float* __restrict__ ATTN) {
    extern __shared__ char dynsm[];
    int idx = blockIdx.x;
    if (idx < 1024) role_pam(dynsm, idx & 31, (idx >> 5) & 3, idx >> 7, QT, KT, VB, OPART, LPART);
    else role_cam_softmax(dynsm, idx - 1024, EPART, ATTN);
}

// ============ fuse3: pam_combine (256 blocks) | cam_apply (128) ============
__device__ void role_pam_combine(char* dynsm, int qt, int b,
        const unsigned short* __restrict__ OPART, const float* __restrict__ LPART,
        const unsigned short* __restrict__ Y1T, const float* __restrict__ STATS1,
        const float* __restrict__ g5a, const float* __restrict__ b5a,
        const float* __restrict__ gamma, unsigned short* __restrict__ SAFT) {
    float* dn = (float*)dynsm;
    float* cA = dn + 64;
    float* cB = cA + 64;
    unsigned short* tile = (unsigned short*)(cB + 64);   // 64*66
    int l0 = qt * 64;
    int t = threadIdx.x;
    load_coef(STATS1, g5a, b5a, 0, 64, cA, cB);
    if (t < 64) {
        size_t lbase = ((size_t)((b * 32 + qt) * 4)) * 64;
        dn[t] = LPART[lbase + t] + LPART[lbase + 64 + t] +
                LPART[lbase + 128 + t] + LPART[lbase + 192 + t];
    }
    __syncthreads();
    int c = t >> 2, qc = t & 3;
    float O[16];
#pragma unroll
    for (int i = 0; i < 16; ++i) O[i] = 0.f;
    size_t ob = ((size_t)((b * 32 + qt) * 4)) * 4096 + c * 64 + qc * 16;
#pragma unroll
    for (int s = 0; s < 4; ++s) {
        bshort8 p0 = *(const bshort8*)(OPART + ob + (size_t)s * 4096);
        bshort8 p1 = *(const bshort8*)(OPART + ob + (size_t)s * 4096 + 8);
#pragma unroll
        for (int i = 0; i < 8; ++i) {
            O[i]     += bf2f((unsigned short)p0[i]);
            O[8 + i] += bf2f((unsigned short)p1[i]);
        }
    }
    float gm = gamma[0];
#pragma unroll
    for (int i = 0; i < 16; ++i) {
        int q = qc * 16 + i;
        unsigned short raw = Y1T[((size_t)(b * LP + l0 + q)) * IC + c];
        float f1v = fmaxf(fmaf(cA[c], bf2f(raw), cB[c]), 0.f);
        float val = fmaf(gm, O[i] / dn[q], f1v);
        tile[q * 66 + c] = f2bf(val);
    }
    __syncthreads();
    int li = t >> 2, cc = t & 3;
    unsigned int* dst = (unsigned int*)(SAFT + ((size_t)(b * LP + l0 + li)) * IC + cc * 16);
#pragma unroll
    for (int i = 0; i < 8; ++i)
        dst[i] = *(unsigned int*)(tile + li * 66 + cc * 16 + 2 * i);
}

__device__ void role_cam_apply(char* dynsm, int blkx, int b,
        const float* __restrict__ attn, const unsigned short* __restrict__ Y2C,
        const float* __restrict__ STATS1,
        const float* __restrict__ g5c, const float* __restrict__ b5c,
        const float* __restrict__ gamma, unsigned short* __restrict__ SCFT) {
    float* as = (float*)dynsm;                    // 4096 floats
    float* cA = as + 4096;
    float* cB = cA + 64;
    unsigned short* tile = (unsigned short*)(cB + 64);  // 128*66
    int l0 = blkx * 128;
    int t = threadIdx.x;
    int lq = t & 127, ch = t >> 7;
    load_coef(STATS1, g5c, b5c, 64, 64, cA, cB);
    for (int i = t; i < 4096; i += 256) as[i] = attn[(size_t)b * 4096 + i];
    __syncthreads();
    float acc[32];
#pragma unroll
    for (int i = 0; i < 32; ++i) acc[i] = 0.f;
    const unsigned short* fb = Y2C + (size_t)b * IC * LP + l0 + lq;
    for (int d4 = 0; d4 < 16; ++d4) {
        float fv[4];
#pragma unroll
        for (int i = 0; i < 4; ++i) {
            int d = 4 * d4 + i;
            fv[i] = fmaxf(fmaf(cA[d], bf2f(fb[(size_t)d * LP]), cB[d]), 0.f);
        }
#pragma unroll
        for (int cc = 0; cc < 32; ++cc) {
            const float4 a4 = *reinterpret_cast<const float4*>(as + (ch * 32 + cc) * 64 + d4 * 4);
            acc[cc] += a4.x * fv[0] + a4.y * fv[1] + a4.z * fv[2] + a4.w * fv[3];
        }
    }
    float gm = gamma[0];
#pragma unroll
    for (int cc = 0; cc < 32; ++cc) {
        int c = ch * 32 + cc;
        float res = fmaxf(fmaf(cA[c], bf2f(fb[(size_t)c * LP]), cB[c]), 0.f);
        tile[lq * 66 + c] = f2bf(fmaf(gm, acc[cc], res));
    }
    __syncthreads();
    int li = t >> 1, half = t & 1;
    unsigned int* dst = (unsigned int*)(SCFT + ((size_t)(b * LP + l0 + li)) * IC + half * 32);
#pragma unroll
    for (int i = 0; i < 16; ++i)
        dst[i] = *(unsigned int*)(tile + li * 66 + half * 32 + 2 * i);
}

__global__ __launch_bounds__(256) void k_fuse3(
        const unsigned short* __restrict__ OPART, const float* __restrict__ LPART,
        const unsigned short* __restrict__ Y1T, const unsigned short* __restrict__ Y2C,
        const float* __restrict__ STATS1,
        const float* __restrict__ g5a, const float* __restrict__ b5a,
        const float* __restrict__ g5c, const float* __restrict__ b5c,
        const float* __restrict__ gpam, const float* __restrict__ gcam,
        const float* __restrict__ ATTN,
        unsigned short* __restrict__ SAFT, unsigned short* __restrict__ SCFT) {
    extern __shared__ char dynsm[];
    int idx = blockIdx.x;
    if (idx < 256) role_pam_combine(dynsm, idx & 31, idx >> 5, OPART, LPART, Y1T,
                                    STATS1, g5a, b5a, gpam, SAFT);
    else { int g = idx - 256; role_cam_apply(dynsm, g & 15, g >> 4, ATTN, Y2C,
                                             STATS1, g5c, b5c, gcam, SCFT); }
}

// ---- conv3 (both branches) -> pre-BN bf16 + atomic stats ----
__global__ __launch_bounds__(256) void k_conv3(const unsigned short* __restrict__ SAFT,
        const unsigned short* __restrict__ SCFT, const unsigned short* __restrict__ WTall,
        unsigned short* __restrict__ Y51T, unsigned short* __restrict__ Y52T,
        float* __restrict__ STATS2) {
    __shared__ float lds_part[4][128];
    int lt = blockIdx.x, og = blockIdx.y, b = blockIdx.z;
    const unsigned short* FTsrc = og ? SCFT : SAFT;
    const unsigned short* WT = WTall + og * 12288;
    unsigned short* dst = og ? Y52T : Y51T;
    int l0 = lt * 64;
    int w = threadIdx.x >> 6, lane = threadIdx.x & 63, n = lane & 15, quad = lane >> 4;
    int lrow = l0 + w * 16 + n;
    f32x4 acc[4];
#pragma unroll
    for (int ot = 0; ot < 4; ++ot) acc[ot] = (f32x4){0.f, 0.f, 0.f, 0.f};
#pragma unroll
    for (int t3 = 0; t3 < 3; ++t3) {
        int row = lrow + t3 - 1;
        bshort8 fb[2];
#pragma unroll
        for (int kt = 0; kt < 2; ++kt) {
            if (row >= 0 && row < LP)
                fb[kt] = *(const bshort8*)(FTsrc + ((size_t)(b * LP + row)) * IC + kt * 32 + quad * 8);
            else fb[kt] = (bshort8){};
        }
#pragma unroll
        for (int ot = 0; ot < 4; ++ot)
#pragma unroll
            for (int kt = 0; kt < 2; ++kt) {
                bshort8 wf = *(const bshort8*)(WT + ((size_t)(t3 * 64 + ot * 16 + n)) * IC + kt * 32 + quad * 8);
                acc[ot] = __builtin_amdgcn_mfma_f32_16x16x32_bf16(wf, fb[kt], acc[ot], 0, 0, 0);
            }
    }
#pragma unroll
    for (int ot = 0; ot < 4; ++ot) {
        uint2 pv;
        pv.x = pk2(acc[ot][0], acc[ot][1]);
        pv.y = pk2(acc[ot][2], acc[ot][3]);
        *(uint2*)(dst + ((size_t)(b * LP + lrow)) * IC + ot * 16 + quad * 4) = pv;
    }
#pragma unroll
    for (int ot = 0; ot < 4; ++ot)
#pragma unroll
        for (int r = 0; r < 4; ++r) {
            float s = acc[ot][r], q = s * s;
#pragma unroll
            for (int msk = 1; msk < 16; msk <<= 1) {
                s += __shfl_xor(s, msk, 64);
                q += __shfl_xor(q, msk, 64);
            }
            if (n == 0) {
                int cch = ot * 16 + quad * 4 + r;
                lds_part[w][cch * 2] = s;
                lds_part[w][cch * 2 + 1] = q;
            }
        }
    __syncthreads();
    int t = threadIdx.x;
    if (t < 128) {
        float s = lds_part[0][t] + lds_part[1][t] + lds_part[2][t] + lds_part[3][t];
        atomicAdd(&STATS2[og * 128 + t], s);
    }
}

// ---- final conv1x1 pair + fused sasc projection (out pre-initialized to b8) ----
__global__ __launch_bounds__(256) void k_final(const unsigned short* __restrict__ Y51T,
        const unsigned short* __restrict__ Y52T, const float* __restrict__ STATS2,
        const float* __restrict__ g51, const float* __restrict__ b51,
        const float* __restrict__ g52, const float* __restrict__ b52,
        const unsigned short* __restrict__ W67,
        const float* __restrict__ b6, const float* __restrict__ b7,
        const float* __restrict__ W8,
        float* __restrict__ out_sa, float* __restrict__ out_sc,
        float* __restrict__ out_sasc) {
    __shared__ float cA[128], cB[128];
    __shared__ float fsw[4][64];
    __shared__ float chsum[64];
    int lt = blockIdx.x, og = blockIdx.y, b = blockIdx.z;
    int t = threadIdx.x;
    {   // BN coefs for both conv3 branches
        if (t < 64) {
            float s = STATS2[t * 2], q = STATS2[t * 2 + 1];
            float mu = s * INVN, var = q * INVN - mu * mu;
            float A = g51[t] * rsqrtf(var + BN_EPS);
            cA[t] = A; cB[t] = b51[t] - mu * A;
        } else if (t < 128) {
            int c = t - 64;
            float s = STATS2[t * 2], q = STATS2[t * 2 + 1];
            float mu = s * INVN, var = q * INVN - mu * mu;
            float A = g52[c] * rsqrtf(var + BN_EPS);
            cA[t] = A; cB[t] = b52[c] - mu * A;
        }
    }
    __syncthreads();
    int w = t >> 6, lane = t & 63, n = lane & 15, quad = lane >> 4;
    int lrow = lt * 64 + w * 16 + n;
    float fs_lane[16];
    bshort8 ba[2], bb[2];
#pragma unroll
    for (int kt = 0; kt < 2; ++kt) {
        bshort8 ra = *(const bshort8*)(Y51T + ((size_t)(b * LP + lrow)) * IC + kt * 32 + quad * 8);
        bshort8 rb = *(const bshort8*)(Y52T + ((size_t)(b * LP + lrow)) * IC + kt * 32 + quad * 8);
        bshort8 fa, fb;
#pragma unroll
        for (int j = 0; j < 8; ++j) {
            int c = kt * 32 + quad * 8 + j;
            float v1 = fmaxf(fmaf(cA[c], bf2f((unsigned short)ra[j]), cB[c]), 0.f);
            float v2 = fmaxf(fmaf(cA[64 + c], bf2f((unsigned short)rb[j]), cB[64 + c]), 0.f);
            ((unsigned short*)&fa)[j] = f2bf(v1);
            ((unsigned short*)&fb)[j] = f2bf(v2);
            fs_lane[kt * 8 + j] = v1 + v2;
        }
        ba[kt] = fa; bb[kt] = fb;
    }
    f32x4 accA[4], accB[4];
#pragma unroll
    for (int ot = 0; ot < 4; ++ot) {
        accA[ot] = (f32x4){0.f, 0.f, 0.f, 0.f};
        accB[ot] = (f32x4){0.f, 0.f, 0.f, 0.f};
    }
#pragma unroll
    for (int ot = 0; ot < 4; ++ot)
#pragma unroll
        for (int kt = 0; kt < 2; ++kt) {
            bshort8 wa = *(const bshort8*)(W67 + (size_t)(og * 64 + ot * 16 + n) * IC + kt * 32 + quad * 8);
            bshort8 wb = *(const bshort8*)(W67 + 8192 + (size_t)(og * 64 + ot * 16 + n) * IC + kt * 32 + quad * 8);
            accA[ot] = __builtin_amdgcn_mfma_f32_16x16x32_bf16(wa, ba[kt], accA[ot], 0, 0, 0);
            accB[ot] = __builtin_amdgcn_mfma_f32_16x16x32_bf16(wb, bb[kt], accB[ot], 0, 0, 0);
        }
#pragma unroll
    for (int ot = 0; ot < 4; ++ot)
#pragma unroll
        for (int r = 0; r < 4; ++r) {
            int o = og * 64 + ot * 16 + quad * 4 + r;
            out_sa[((size_t)(b * OC + o)) * LP + lrow] = accA[ot][r] + b6[o];
            out_sc[((size_t)(b * OC + o)) * LP + lrow] = accB[ot][r] + b7[o];
        }
    if (og == 0) {
#pragma unroll
        for (int i = 0; i < 16; ++i) {
            float s = fs_lane[i];
#pragma unroll
            for (int msk = 1; msk < 16; msk <<= 1) s += __shfl_xor(s, msk, 64);
            if (n == 0) {
                int c = (i >> 3) * 32 + quad * 8 + (i & 7);
                fsw[w][c] = s;
            }
        }
        __syncthreads();
        if (t < 64) chsum[t] = fsw[0][t] + fsw[1][t] + fsw[2][t] + fsw[3][t];
        __syncthreads();
        if (t < 128) {
            float s = 0.f;
            for (int c = 0; c < 64; ++c) s = fmaf(W8[t * 64 + c], chsum[c], s);
            atomicAdd(&out_sasc[b * OC + t], s * (1.f / (float)LP));
        }
    }
}

extern "C" void kernel_launch(void* const* d_in, const int* in_sizes, int n_in,
                              void* d_out, int out_size, void* d_ws, size_t ws_size,
                              hipStream_t stream) {
    (void)in_sizes; (void)n_in; (void)out_size; (void)ws_size;
    const float* x    = (const float*)d_in[0];
    const float* W5a  = (const float*)d_in[1];
    const float* g5a  = (const float*)d_in[2];
    const float* b5a  = (const float*)d_in[3];
    const float* W5c  = (const float*)d_in[4];
    const float* g5c  = (const float*)d_in[5];
    const float* b5c  = (const float*)d_in[6];
    const float* Wq   = (const float*)d_in[7];
    const float* bq   = (const float*)d_in[8];
    const float* Wk   = (const float*)d_in[9];
    const float* bk   = (const float*)d_in[10];
    const float* Wv   = (const float*)d_in[11];
    const float* bv   = (const float*)d_in[12];
    const float* gpam = (const float*)d_in[13];
    const float* gcam = (const float*)d_in[14];
    const float* W51  = (const float*)d_in[15];
    const float* g51  = (const float*)d_in[16];
    const float* b51  = (const float*)d_in[17];
    const float* W52  = (const float*)d_in[18];
    const float* g52  = (const float*)d_in[19];
    const float* b52  = (const float*)d_in[20];
    const float* W6   = (const float*)d_in[21];
    const float* b6   = (const float*)d_in[22];
    const float* W7   = (const float*)d_in[23];
    const float* b7   = (const float*)d_in[24];
    const float* W8   = (const float*)d_in[25];
    const float* b8   = (const float*)d_in[26];

    float* ws = (float*)d_ws;
    float* out = (float*)d_out;
    unsigned short* Y1T  = (unsigned short*)(ws + OFF_Y1T);
    unsigned short* Y2C  = (unsigned short*)(ws + OFF_Y2C);
    unsigned short* SAFT = (unsigned short*)(ws + OFF_SAFT);
    unsigned short* SCFT = (unsigned short*)(ws + OFF_SCFT);
    unsigned short* Y51T = (unsigned short*)(ws + OFF_Y51T);
    unsigned short* Y52T = (unsigned short*)(ws + OFF_Y52T);
    unsigned short* VB   = (unsigned short*)(ws + OFF_VB);
    unsigned short* QT   = (unsigned short*)(ws + OFF_QT);
    unsigned short* KT   = (unsigned short*)(ws + OFF_KT);
    float* LPART  = ws + OFF_LPART;
    float* EPART  = ws + OFF_EPART;
    float* ATTN   = ws + OFF_ATTN;
    float* STATS1 = ws + OFF_STATS1;
    float* STATS2 = ws + OFF_STATS2;
    unsigned short* W5BF = (unsigned short*)(ws + OFF_W5BF);
    unsigned short* W67  = (unsigned short*)(ws + OFF_W67);
    unsigned short* WT   = (unsigned short*)(ws + OFF_WT);
    unsigned short* WQKV = (unsigned short*)(ws + OFF_WQKV);
    float* BQKV = ws + OFF_BQKV;

    float* out_sa = out + B * OC;
    float* out_sc = out + B * OC + (size_t)B * OC * LP;
    unsigned short* OPART = (unsigned short*)out_sa;  // scratch, overwritten by k_final

    k_wprep<<<315, 256, 0, stream>>>(W5a, W5c, W6, W7, W51, W52, Wq, Wk, Wv,
                                     bq, bk, bv, b8, W5BF, W67, WT, WQKV, BQKV,
                                     STATS1, STATS2, out);
    k_conv1<<<dim3(32, 2, B), 256, 0, stream>>>(x, W5BF, Y1T, Y2C, STATS1);
    k_fuse1<<<288, 256, 512, stream>>>(Y1T, Y2C, STATS1, g5a, b5a, g5c, b5c,
                                       WQKV, BQKV, QT, KT, VB, EPART);
    k_fuse2<<<1032, 256, 18432, stream>>>(QT, KT, VB, OPART, LPART, EPART, ATTN);
    k_fuse3<<<384, 256, 33792, stream>>>(OPART, LPART, Y1T, Y2C, STATS1,
                                         g5a, b5a, g5c, b5c, gpam, gcam, ATTN,
                                         SAFT, SCFT);
    k_conv3<<<dim3(32, 2, B), 256, 0, stream>>>(SAFT, SCFT, WT, Y51T, Y52T, STATS2);
    k_final<<<dim3(32, 2, B), 256, 0, stream>>>(Y51T, Y52T, STATS2, g51, b51, g52, b52,
                                                W67, b6, b7, W8, out_sa, out_sc, out);
}